// Round 1
// baseline (2842.372 us; speedup 1.0000x reference)
//
#include <hip/hip_runtime.h>

#define D_MODEL 1024
#define NHEADS  16
#define DK      64
#define S_LEN   2048
#define BATCH   4
#define BH      (BATCH * NHEADS)     // 64
#define M_ROWS  (BATCH * S_LEN)      // 8192

// compat = (1 + sqrt(max(d2,0))/64)^(-65), via 6 squarings (exact integer power)
__device__ __forceinline__ float compat_fn(float d2) {
    d2 = fmaxf(d2, 0.0f);
    float g = sqrtf(d2) * 0.015625f;   // / DIST_SCALE (=64)
    float p = 1.0f + g;                // / sqrt(BANDWIDTH) (=1)
    float p2  = p   * p;
    float p4  = p2  * p2;
    float p8  = p4  * p4;
    float p16 = p8  * p8;
    float p32 = p16 * p16;
    float p64 = p32 * p32;
    return 1.0f / (p64 * p);           // p^-65
}

// out = X @ W^T (+bias). X[M,1024] rm, W[1024,1024] rm.
// MODE 0: write head-split dst[((b*16+h)*2048+s)*64+d]   (m=b*2048+s, n=h*64+d)
// MODE 1: dst[m*1024+n] = acc + bias[n]
template <int MODE>
__global__ __launch_bounds__(256) void proj_gemm(const float* __restrict__ X,
                                                 const float* __restrict__ W,
                                                 const float* __restrict__ bias,
                                                 float* __restrict__ dst) {
    __shared__ __align__(16) float XsT[32][132];   // [k][m_local]
    __shared__ __align__(16) float WsT[32][132];   // [k][n_local]
    const int tx = threadIdx.x;   // 0..15
    const int ty = threadIdx.y;   // 0..15
    const int tid = ty * 16 + tx;
    const int n0 = blockIdx.x * 128;
    const int m0 = blockIdx.y * 128;

    float acc[8][8] = {};

    for (int k0 = 0; k0 < D_MODEL; k0 += 32) {
#pragma unroll
        for (int l = 0; l < 4; ++l) {
            int idx = tid + l * 256;      // 0..1023
            int row = idx >> 3;           // 0..127
            int c4  = (idx & 7) << 2;     // 0..28
            float4 xv = *(const float4*)&X[(m0 + row) * D_MODEL + k0 + c4];
            XsT[c4 + 0][row] = xv.x; XsT[c4 + 1][row] = xv.y;
            XsT[c4 + 2][row] = xv.z; XsT[c4 + 3][row] = xv.w;
            float4 wv = *(const float4*)&W[(n0 + row) * D_MODEL + k0 + c4];
            WsT[c4 + 0][row] = wv.x; WsT[c4 + 1][row] = wv.y;
            WsT[c4 + 2][row] = wv.z; WsT[c4 + 3][row] = wv.w;
        }
        __syncthreads();
#pragma unroll 8
        for (int kk = 0; kk < 32; ++kk) {
            float4 a0 = *(const float4*)&XsT[kk][ty * 8];
            float4 a1 = *(const float4*)&XsT[kk][ty * 8 + 4];
            float4 b0 = *(const float4*)&WsT[kk][tx * 8];
            float4 b1 = *(const float4*)&WsT[kk][tx * 8 + 4];
            float av[8] = {a0.x, a0.y, a0.z, a0.w, a1.x, a1.y, a1.z, a1.w};
            float bv[8] = {b0.x, b0.y, b0.z, b0.w, b1.x, b1.y, b1.z, b1.w};
#pragma unroll
            for (int i = 0; i < 8; ++i)
#pragma unroll
                for (int j = 0; j < 8; ++j)
                    acc[i][j] = fmaf(av[i], bv[j], acc[i][j]);
        }
        __syncthreads();
    }

#pragma unroll
    for (int i = 0; i < 8; ++i) {
        int m = m0 + ty * 8 + i;
#pragma unroll
        for (int j = 0; j < 8; ++j) {
            int n = n0 + tx * 8 + j;
            if (MODE == 0) {
                int b = m >> 11, s = m & 2047;
                int h = n >> 6,  d = n & 63;
                dst[(((b << 4) + h) * S_LEN + s) * DK + d] = acc[i][j];
            } else {
                dst[m * D_MODEL + n] = acc[i][j] + bias[n];
            }
        }
    }
}

// squared L2 norms of Q rows and K rows ([BH*S] each); one wave per row
__global__ __launch_bounds__(256) void row_norms(const float* __restrict__ Q,
                                                 const float* __restrict__ K,
                                                 float* __restrict__ q2,
                                                 float* __restrict__ k2) {
    int wid  = blockIdx.x * 4 + (threadIdx.x >> 6);
    int lane = threadIdx.x & 63;
    const float* src; float* dstp; int row;
    if (wid < BH * S_LEN) { src = Q; dstp = q2; row = wid; }
    else                  { src = K; dstp = k2; row = wid - BH * S_LEN; }
    float v = src[row * DK + lane];
    float s = v * v;
#pragma unroll
    for (int off = 32; off > 0; off >>= 1) s += __shfl_xor(s, off);
    if (lane == 0) dstp[row] = s;
}

// Pass A: column sums N_C[t] = sum_s compat[s,t]. Block owns (bh, 64 t-columns).
__global__ __launch_bounds__(256) void pass_colsum(const float* __restrict__ Q,
                                                   const float* __restrict__ K,
                                                   const float* __restrict__ q2,
                                                   const float* __restrict__ k2,
                                                   float* __restrict__ NC) {
    __shared__ __align__(16) float KsT[64][68];   // [dim][t_local]
    __shared__ __align__(16) float QsT[64][68];   // [dim][s_local]
    __shared__ float red[16][64];
    const int tx = threadIdx.x, ty = threadIdx.y;
    const int tid = ty * 16 + tx;
    const int bh = blockIdx.y;
    const int t0 = blockIdx.x * 64;
    const float* Qb = Q + bh * (S_LEN * DK);
    const float* Kb = K + bh * (S_LEN * DK);

#pragma unroll
    for (int l = 0; l < 4; ++l) {
        int idx = tid + l * 256;
        int row = idx >> 4;            // 0..63
        int c4  = (idx & 15) << 2;     // 0..60
        float4 kv = *(const float4*)&Kb[(t0 + row) * DK + c4];
        KsT[c4 + 0][row] = kv.x; KsT[c4 + 1][row] = kv.y;
        KsT[c4 + 2][row] = kv.z; KsT[c4 + 3][row] = kv.w;
    }
    float k2v[4];
#pragma unroll
    for (int j = 0; j < 4; ++j) k2v[j] = k2[bh * S_LEN + t0 + tx * 4 + j];

    float colacc[4] = {0.f, 0.f, 0.f, 0.f};

    for (int s0 = 0; s0 < S_LEN; s0 += 64) {
        __syncthreads();
#pragma unroll
        for (int l = 0; l < 4; ++l) {
            int idx = tid + l * 256;
            int row = idx >> 4;
            int c4  = (idx & 15) << 2;
            float4 qv = *(const float4*)&Qb[(s0 + row) * DK + c4];
            QsT[c4 + 0][row] = qv.x; QsT[c4 + 1][row] = qv.y;
            QsT[c4 + 2][row] = qv.z; QsT[c4 + 3][row] = qv.w;
        }
        __syncthreads();
        float dot[4][4] = {};
#pragma unroll 16
        for (int kk = 0; kk < 64; ++kk) {
            float4 a  = *(const float4*)&QsT[kk][ty * 4];
            float4 b4 = *(const float4*)&KsT[kk][tx * 4];
            float av[4] = {a.x, a.y, a.z, a.w};
            float bv[4] = {b4.x, b4.y, b4.z, b4.w};
#pragma unroll
            for (int i = 0; i < 4; ++i)
#pragma unroll
                for (int j = 0; j < 4; ++j)
                    dot[i][j] = fmaf(av[i], bv[j], dot[i][j]);
        }
#pragma unroll
        for (int i = 0; i < 4; ++i) {
            float q2i = q2[bh * S_LEN + s0 + ty * 4 + i];
#pragma unroll
            for (int j = 0; j < 4; ++j) {
                float d2 = q2i + k2v[j] - 2.0f * dot[i][j];
                colacc[j] += compat_fn(d2);
            }
        }
    }
#pragma unroll
    for (int j = 0; j < 4; ++j) red[ty][tx * 4 + j] = colacc[j];
    __syncthreads();
    if (tid < 64) {
        float s = 0.f;
#pragma unroll
        for (int r = 0; r < 16; ++r) s += red[r][tid];
        NC[bh * S_LEN + t0 + tid] = s;
    }
}

// Pass B: flash-style. Block owns (bh, 64 s-rows); iterates t-tiles.
// w = compat * NC^-0.5; O += w @ V; D = row-sum(w); attn = O/D -> merged layout.
__global__ __launch_bounds__(256) void pass_attn(const float* __restrict__ Q,
                                                 const float* __restrict__ K,
                                                 const float* __restrict__ V,
                                                 const float* __restrict__ q2,
                                                 const float* __restrict__ k2,
                                                 const float* __restrict__ NC,
                                                 float* __restrict__ ATTN) {
    __shared__ __align__(16) float QsT[64][68];   // [dim][s_local]
    __shared__ __align__(16) float KsT[64][68];   // [dim][t_local]
    __shared__ __align__(16) float Vs[64][68];    // [t_local][dim]
    __shared__ __align__(16) float Ws[64][68];    // [s_local][t_local]
    __shared__ float red[16][64];
    __shared__ float Drow[64];
    const int tx = threadIdx.x, ty = threadIdx.y;
    const int tid = ty * 16 + tx;
    const int bh = blockIdx.y;
    const int s0 = blockIdx.x * 64;
    const int b = bh >> 4, h = bh & 15;
    const float* Qb = Q + bh * (S_LEN * DK);
    const float* Kb = K + bh * (S_LEN * DK);
    const float* Vb = V + bh * (S_LEN * DK);

#pragma unroll
    for (int l = 0; l < 4; ++l) {
        int idx = tid + l * 256;
        int row = idx >> 4;
        int c4  = (idx & 15) << 2;
        float4 qv = *(const float4*)&Qb[(s0 + row) * DK + c4];
        QsT[c4 + 0][row] = qv.x; QsT[c4 + 1][row] = qv.y;
        QsT[c4 + 2][row] = qv.z; QsT[c4 + 3][row] = qv.w;
    }
    float q2v[4];
#pragma unroll
    for (int i = 0; i < 4; ++i) q2v[i] = q2[bh * S_LEN + s0 + ty * 4 + i];

    float o[4][4] = {};
    float rowacc[4] = {0.f, 0.f, 0.f, 0.f};

    for (int t0 = 0; t0 < S_LEN; t0 += 64) {
        __syncthreads();   // prev-iter PV reads done before overwriting K/V/W tiles
#pragma unroll
        for (int l = 0; l < 4; ++l) {
            int idx = tid + l * 256;
            int row = idx >> 4;
            int c4  = (idx & 15) << 2;
            float4 kv = *(const float4*)&Kb[(t0 + row) * DK + c4];
            KsT[c4 + 0][row] = kv.x; KsT[c4 + 1][row] = kv.y;
            KsT[c4 + 2][row] = kv.z; KsT[c4 + 3][row] = kv.w;
            float4 vv = *(const float4*)&Vb[(t0 + row) * DK + c4];
            *(float4*)&Vs[row][c4] = vv;
        }
        float k2v[4], cv[4];
#pragma unroll
        for (int j = 0; j < 4; ++j) {
            int t = bh * S_LEN + t0 + tx * 4 + j;
            k2v[j] = k2[t];
            cv[j]  = 1.0f / sqrtf(NC[t]);   // N_C^(-0.5)
        }
        __syncthreads();
        float dot[4][4] = {};
#pragma unroll 16
        for (int kk = 0; kk < 64; ++kk) {
            float4 a  = *(const float4*)&QsT[kk][ty * 4];
            float4 b4 = *(const float4*)&KsT[kk][tx * 4];
            float av[4] = {a.x, a.y, a.z, a.w};
            float bv[4] = {b4.x, b4.y, b4.z, b4.w};
#pragma unroll
            for (int i = 0; i < 4; ++i)
#pragma unroll
                for (int j = 0; j < 4; ++j)
                    dot[i][j] = fmaf(av[i], bv[j], dot[i][j]);
        }
#pragma unroll
        for (int i = 0; i < 4; ++i)
#pragma unroll
            for (int j = 0; j < 4; ++j) {
                float d2 = q2v[i] + k2v[j] - 2.0f * dot[i][j];
                float w  = compat_fn(d2) * cv[j];
                rowacc[i] += w;
                Ws[ty * 4 + i][tx * 4 + j] = w;
            }
        __syncthreads();
#pragma unroll 8
        for (int t = 0; t < 64; ++t) {
            float4 v4 = *(const float4*)&Vs[t][tx * 4];
            float w0 = Ws[ty * 4 + 0][t];
            float w1 = Ws[ty * 4 + 1][t];
            float w2 = Ws[ty * 4 + 2][t];
            float w3 = Ws[ty * 4 + 3][t];
            o[0][0] = fmaf(w0, v4.x, o[0][0]); o[0][1] = fmaf(w0, v4.y, o[0][1]);
            o[0][2] = fmaf(w0, v4.z, o[0][2]); o[0][3] = fmaf(w0, v4.w, o[0][3]);
            o[1][0] = fmaf(w1, v4.x, o[1][0]); o[1][1] = fmaf(w1, v4.y, o[1][1]);
            o[1][2] = fmaf(w1, v4.z, o[1][2]); o[1][3] = fmaf(w1, v4.w, o[1][3]);
            o[2][0] = fmaf(w2, v4.x, o[2][0]); o[2][1] = fmaf(w2, v4.y, o[2][1]);
            o[2][2] = fmaf(w2, v4.z, o[2][2]); o[2][3] = fmaf(w2, v4.w, o[2][3]);
            o[3][0] = fmaf(w3, v4.x, o[3][0]); o[3][1] = fmaf(w3, v4.y, o[3][1]);
            o[3][2] = fmaf(w3, v4.z, o[3][2]); o[3][3] = fmaf(w3, v4.w, o[3][3]);
        }
    }

#pragma unroll
    for (int i = 0; i < 4; ++i) red[tx][ty * 4 + i] = rowacc[i];
    __syncthreads();
    if (tid < 64) {
        float s = 0.f;
#pragma unroll
        for (int r = 0; r < 16; ++r) s += red[r][tid];
        Drow[tid] = s;
    }
    __syncthreads();
#pragma unroll
    for (int i = 0; i < 4; ++i) {
        float dr = Drow[ty * 4 + i];
        int srow = s0 + ty * 4 + i;
#pragma unroll
        for (int j = 0; j < 4; ++j)
            ATTN[(b * S_LEN + srow) * D_MODEL + h * DK + tx * 4 + j] = o[i][j] / dr;
    }
}

extern "C" void kernel_launch(void* const* d_in, const int* in_sizes, int n_in,
                              void* d_out, int out_size, void* d_ws, size_t ws_size,
                              hipStream_t stream) {
    const float* queries = (const float*)d_in[0];
    const float* keys    = (const float*)d_in[1];
    const float* values  = (const float*)d_in[2];
    const float* Wq      = (const float*)d_in[3];
    const float* Wk      = (const float*)d_in[4];
    const float* Wv      = (const float*)d_in[5];
    const float* Wo      = (const float*)d_in[6];
    const float* bo      = (const float*)d_in[7];
    float* out = (float*)d_out;

    float* ws = (float*)d_ws;
    const size_t QKV = (size_t)BH * S_LEN * DK;   // 8388608
    float* Q    = ws;
    float* K    = Q + QKV;
    float* V    = K + QKV;
    float* q2   = V + QKV;                        // BH*S
    float* k2   = q2 + (size_t)BH * S_LEN;
    float* NC   = k2 + (size_t)BH * S_LEN;
    float* ATTN = NC + (size_t)BH * S_LEN;        // 8388608

    dim3 blk(16, 16);
    dim3 gproj(D_MODEL / 128, M_ROWS / 128);      // (8, 64)
    proj_gemm<0><<<gproj, blk, 0, stream>>>(queries, Wq, nullptr, Q);
    proj_gemm<0><<<gproj, blk, 0, stream>>>(keys,    Wk, nullptr, K);
    proj_gemm<0><<<gproj, blk, 0, stream>>>(values,  Wv, nullptr, V);

    row_norms<<<(2 * BH * S_LEN) / 4, 256, 0, stream>>>(Q, K, q2, k2);

    dim3 gpass(S_LEN / 64, BH);                   // (32, 64)
    pass_colsum<<<gpass, blk, 0, stream>>>(Q, K, q2, k2, NC);
    pass_attn<<<gpass, blk, 0, stream>>>(Q, K, V, q2, k2, NC, ATTN);

    proj_gemm<1><<<gproj, blk, 0, stream>>>(ATTN, Wo, bo, out);
}

// Round 2
// 1906.730 us; speedup vs baseline: 1.4907x; 1.4907x over previous
//
#include <hip/hip_runtime.h>

#define D_MODEL 1024
#define NHEADS  16
#define DK      64
#define S_LEN   2048
#define BATCH   4
#define BH      (BATCH * NHEADS)     // 64
#define M_ROWS  (BATCH * S_LEN)      // 8192

typedef float  f32x4 __attribute__((ext_vector_type(4)));
typedef short  s16x8 __attribute__((ext_vector_type(8)));
typedef unsigned short us8 __attribute__((ext_vector_type(8)));

__device__ __forceinline__ unsigned short f2bf(float f) {
    unsigned u = __builtin_bit_cast(unsigned, f);
    u += 0x7FFFu + ((u >> 16) & 1u);
    return (unsigned short)(u >> 16);
}
__device__ __forceinline__ float bf2f(unsigned short b) {
    unsigned u = ((unsigned)b) << 16;
    return __builtin_bit_cast(float, u);
}

// compat = (1 + sqrt(max(d2,0))/64)^(-65) via 6 squarings (exact integer power)
__device__ __forceinline__ float compat_fn(float d2) {
    d2 = fmaxf(d2, 0.0f);
    float g = __builtin_amdgcn_sqrtf(d2) * 0.015625f;
    float p = 1.0f + g;
    float p2  = p   * p;
    float p4  = p2  * p2;
    float p8  = p4  * p4;
    float p16 = p8  * p8;
    float p32 = p16 * p16;
    float p64 = p32 * p32;
    return __builtin_amdgcn_rcpf(p64 * p);   // p^-65
}

// out = X @ W^T (+bias). X[M,1024] rm, W[1024,1024] rm.
// MODE 0: head-split hi/lo bf16: dst[((b*16+h)*2048+s)*64+d]
// MODE 2: head-split TRANSPOSED hi/lo bf16: dst[((b*16+h)*64+d)*2048+s]  (for V)
// MODE 1: fp32 dst[m*1024+n] = acc + bias[n]
template <int MODE>
__global__ __launch_bounds__(256) void proj_gemm(const float* __restrict__ X,
                                                 const float* __restrict__ W,
                                                 const float* __restrict__ bias,
                                                 float* __restrict__ outf,
                                                 unsigned short* __restrict__ ohi,
                                                 unsigned short* __restrict__ olo) {
    __shared__ __align__(16) float XsT[32][132];   // [k][m_local]
    __shared__ __align__(16) float WsT[32][132];   // [k][n_local]
    const int tx = threadIdx.x;   // 0..15
    const int ty = threadIdx.y;   // 0..15
    const int tid = ty * 16 + tx;
    const int n0 = blockIdx.x * 128;
    const int m0 = blockIdx.y * 128;

    float acc[8][8] = {};

    for (int k0 = 0; k0 < D_MODEL; k0 += 32) {
#pragma unroll
        for (int l = 0; l < 4; ++l) {
            int idx = tid + l * 256;      // 0..1023
            int row = idx >> 3;           // 0..127
            int c4  = (idx & 7) << 2;     // 0..28
            float4 xv = *(const float4*)&X[(size_t)(m0 + row) * D_MODEL + k0 + c4];
            XsT[c4 + 0][row] = xv.x; XsT[c4 + 1][row] = xv.y;
            XsT[c4 + 2][row] = xv.z; XsT[c4 + 3][row] = xv.w;
            float4 wv = *(const float4*)&W[(size_t)(n0 + row) * D_MODEL + k0 + c4];
            WsT[c4 + 0][row] = wv.x; WsT[c4 + 1][row] = wv.y;
            WsT[c4 + 2][row] = wv.z; WsT[c4 + 3][row] = wv.w;
        }
        __syncthreads();
#pragma unroll 8
        for (int kk = 0; kk < 32; ++kk) {
            float4 a0 = *(const float4*)&XsT[kk][ty * 8];
            float4 a1 = *(const float4*)&XsT[kk][ty * 8 + 4];
            float4 b0 = *(const float4*)&WsT[kk][tx * 8];
            float4 b1 = *(const float4*)&WsT[kk][tx * 8 + 4];
            float av[8] = {a0.x, a0.y, a0.z, a0.w, a1.x, a1.y, a1.z, a1.w};
            float bv[8] = {b0.x, b0.y, b0.z, b0.w, b1.x, b1.y, b1.z, b1.w};
#pragma unroll
            for (int i = 0; i < 8; ++i)
#pragma unroll
                for (int j = 0; j < 8; ++j)
                    acc[i][j] = fmaf(av[i], bv[j], acc[i][j]);
        }
        __syncthreads();
    }

    if (MODE == 0) {
        const int h  = (n0 + tx * 8) >> 6;
        const int d0 = (n0 + tx * 8) & 63;
#pragma unroll
        for (int i = 0; i < 8; ++i) {
            const int m = m0 + ty * 8 + i;
            const int b = m >> 11, s = m & 2047;
            us8 hv, lv;
#pragma unroll
            for (int j = 0; j < 8; ++j) {
                float v = acc[i][j];
                unsigned short hb = f2bf(v);
                hv[j] = hb;
                lv[j] = f2bf(v - bf2f(hb));
            }
            size_t idx = ((size_t)((b * NHEADS + h) * S_LEN + s)) * DK + d0;
            *(us8*)(ohi + idx) = hv;
            *(us8*)(olo + idx) = lv;
        }
    } else if (MODE == 2) {
        const int b  = m0 >> 11;
        const int sb = (m0 & 2047) + ty * 8;
#pragma unroll
        for (int j = 0; j < 8; ++j) {
            const int n = n0 + tx * 8 + j;
            const int h = n >> 6, d = n & 63;
            us8 hv, lv;
#pragma unroll
            for (int i = 0; i < 8; ++i) {
                float v = acc[i][j];
                unsigned short hb = f2bf(v);
                hv[i] = hb;
                lv[i] = f2bf(v - bf2f(hb));
            }
            size_t idx = ((size_t)((b * NHEADS + h) * DK + d)) * S_LEN + sb;
            *(us8*)(ohi + idx) = hv;
            *(us8*)(olo + idx) = lv;
        }
    } else {
#pragma unroll
        for (int i = 0; i < 8; ++i) {
            const int m = m0 + ty * 8 + i;
#pragma unroll
            for (int j = 0; j < 8; ++j) {
                const int n = n0 + tx * 8 + j;
                outf[(size_t)m * D_MODEL + n] = acc[i][j] + bias[n];
            }
        }
    }
}

// squared L2 norms of Q rows and K rows from hi+lo bf16; one wave per row
__global__ __launch_bounds__(256) void row_norms(const unsigned short* __restrict__ Qhi,
                                                 const unsigned short* __restrict__ Qlo,
                                                 const unsigned short* __restrict__ Khi,
                                                 const unsigned short* __restrict__ Klo,
                                                 float* __restrict__ q2,
                                                 float* __restrict__ k2) {
    int wid  = blockIdx.x * 4 + (threadIdx.x >> 6);
    int lane = threadIdx.x & 63;
    const unsigned short *hi, *lo; float* dstp; int row;
    if (wid < BH * S_LEN) { hi = Qhi; lo = Qlo; dstp = q2; row = wid; }
    else                  { hi = Khi; lo = Klo; dstp = k2; row = wid - BH * S_LEN; }
    float v = bf2f(hi[(size_t)row * DK + lane]) + bf2f(lo[(size_t)row * DK + lane]);
    float s = v * v;
#pragma unroll
    for (int off = 32; off > 0; off >>= 1) s += __shfl_xor(s, off);
    if (lane == 0) dstp[row] = s;
}

// Pass A (MFMA): column sums NC[t] = sum_s compat[s,t]. Block = (bh, 64 t-cols),
// 4 waves as ws x wt = 2x2 over the 64x64 (s-chunk x t) tile, loop over s.
__global__ __launch_bounds__(256, 2) void colsum_mfma(
    const unsigned short* __restrict__ Qhi, const unsigned short* __restrict__ Qlo,
    const unsigned short* __restrict__ Khi, const unsigned short* __restrict__ Klo,
    const float* __restrict__ q2, const float* __restrict__ k2,
    float* __restrict__ NC) {
    const int tid  = threadIdx.x;
    const int wave = tid >> 6, lane = tid & 63;
    const int ws = wave >> 1, wt = wave & 1;
    const int l15 = lane & 15, lg = lane >> 4;
    const int bh = blockIdx.y;
    const int t0 = blockIdx.x * 64;
    const size_t base = (size_t)bh * S_LEN * DK;
    const unsigned short* Kh = Khi + base;
    const unsigned short* Kl = Klo + base;
    const unsigned short* Qh = Qhi + base;
    const unsigned short* Ql = Qlo + base;
    const float* q2b = q2 + (size_t)bh * S_LEN;
    const float* k2b = k2 + (size_t)bh * S_LEN;

    s16x8 kh[2][2], kl[2][2];
    float k2v[2];
#pragma unroll
    for (int ft = 0; ft < 2; ++ft) {
        const int tr = t0 + wt * 32 + ft * 16 + l15;
#pragma unroll
        for (int kc = 0; kc < 2; ++kc) {
            kh[ft][kc] = *(const s16x8*)(Kh + (size_t)tr * DK + kc * 32 + lg * 8);
            kl[ft][kc] = *(const s16x8*)(Kl + (size_t)tr * DK + kc * 32 + lg * 8);
        }
        k2v[ft] = k2b[tr];
    }
    float colacc[2] = {0.f, 0.f};

    for (int s0 = 0; s0 < S_LEN; s0 += 64) {
        const int sb = s0 + ws * 32;
        s16x8 qh[2][2], ql[2][2];
#pragma unroll
        for (int fs = 0; fs < 2; ++fs) {
            const int qr = sb + fs * 16 + l15;
#pragma unroll
            for (int kc = 0; kc < 2; ++kc) {
                qh[fs][kc] = *(const s16x8*)(Qh + (size_t)qr * DK + kc * 32 + lg * 8);
                ql[fs][kc] = *(const s16x8*)(Ql + (size_t)qr * DK + kc * 32 + lg * 8);
            }
        }
        float q2v[2][4];
#pragma unroll
        for (int fs = 0; fs < 2; ++fs)
#pragma unroll
            for (int i = 0; i < 4; ++i)
                q2v[fs][i] = q2b[sb + fs * 16 + lg * 4 + i];

#pragma unroll
        for (int fs = 0; fs < 2; ++fs)
#pragma unroll
            for (int ft = 0; ft < 2; ++ft) {
                f32x4 acc = {0.f, 0.f, 0.f, 0.f};
#pragma unroll
                for (int kc = 0; kc < 2; ++kc) {
                    acc = __builtin_amdgcn_mfma_f32_16x16x32_bf16(qh[fs][kc], kh[ft][kc], acc, 0, 0, 0);
                    acc = __builtin_amdgcn_mfma_f32_16x16x32_bf16(qh[fs][kc], kl[ft][kc], acc, 0, 0, 0);
                    acc = __builtin_amdgcn_mfma_f32_16x16x32_bf16(ql[fs][kc], kh[ft][kc], acc, 0, 0, 0);
                }
#pragma unroll
                for (int i = 0; i < 4; ++i) {
                    float d2 = q2v[fs][i] + k2v[ft] - 2.0f * acc[i];
                    colacc[ft] += compat_fn(d2);
                }
            }
    }
#pragma unroll
    for (int ft = 0; ft < 2; ++ft) {
        colacc[ft] += __shfl_xor(colacc[ft], 16);
        colacc[ft] += __shfl_xor(colacc[ft], 32);
    }
    __shared__ float cs[4][64];
    if (lg == 0) {   // lanes 0..15
        cs[wave][wt * 32 + l15]      = colacc[0];
        cs[wave][wt * 32 + 16 + l15] = colacc[1];
    }
    __syncthreads();
    if (tid < 64) {
        int wtj = tid >> 5;
        NC[(size_t)bh * S_LEN + t0 + tid] = cs[wtj][tid] + cs[wtj + 2][tid];
    }
}

// Pass B (MFMA, flash-style): block = (bh, 64 s-rows); loop t-chunks of 64.
// QK^T (split-bf16) -> compat*cv -> W hi/lo in LDS -> PV (split-bf16) -> O/rowsum.
__global__ __launch_bounds__(256, 2) void attn_mfma(
    const unsigned short* __restrict__ Qhi, const unsigned short* __restrict__ Qlo,
    const unsigned short* __restrict__ Khi, const unsigned short* __restrict__ Klo,
    const unsigned short* __restrict__ VThi, const unsigned short* __restrict__ VTlo,
    const float* __restrict__ q2, const float* __restrict__ k2,
    const float* __restrict__ NC, float* __restrict__ ATTN) {
    __shared__ __align__(16) unsigned short Wh[64][72];   // [s][t], 144B rows (16B aligned)
    __shared__ __align__(16) unsigned short Wl[64][72];
    __shared__ float rsum[2][64];
    const int tid  = threadIdx.x;
    const int wave = tid >> 6, lane = tid & 63;
    const int ws = wave >> 1, wt = wave & 1;
    const int l15 = lane & 15, lg = lane >> 4;
    const int bh = blockIdx.y;
    const int s0 = blockIdx.x * 64;
    const int b = bh >> 4, h = bh & 15;
    const size_t base = (size_t)bh * S_LEN * DK;
    const unsigned short* Qh = Qhi + base;
    const unsigned short* Ql = Qlo + base;
    const unsigned short* Kh = Khi + base;
    const unsigned short* Kl = Klo + base;
    const unsigned short* Vh = VThi + base;   // per-bh [64][2048]
    const unsigned short* Vl = VTlo + base;
    const float* q2b = q2 + (size_t)bh * S_LEN;
    const float* k2b = k2 + (size_t)bh * S_LEN;
    const float* NCb = NC + (size_t)bh * S_LEN;

    // resident Q fragments for this wave's s-half
    s16x8 qh[2][2], qlr[2][2];
#pragma unroll
    for (int fs = 0; fs < 2; ++fs) {
        const int qr = s0 + ws * 32 + fs * 16 + l15;
#pragma unroll
        for (int kc = 0; kc < 2; ++kc) {
            qh[fs][kc]  = *(const s16x8*)(Qh + (size_t)qr * DK + kc * 32 + lg * 8);
            qlr[fs][kc] = *(const s16x8*)(Ql + (size_t)qr * DK + kc * 32 + lg * 8);
        }
    }
    float q2v[2][4];
#pragma unroll
    for (int fs = 0; fs < 2; ++fs)
#pragma unroll
        for (int i = 0; i < 4; ++i)
            q2v[fs][i] = q2b[s0 + ws * 32 + fs * 16 + lg * 4 + i];

    f32x4 o[2][2];
#pragma unroll
    for (int fs = 0; fs < 2; ++fs)
#pragma unroll
        for (int fd = 0; fd < 2; ++fd)
            o[fs][fd] = (f32x4){0.f, 0.f, 0.f, 0.f};
    float rowacc[2][4] = {};

    for (int t0 = 0; t0 < S_LEN; t0 += 64) {
        s16x8 kh[2][2], kl[2][2];
        float k2v[2], cv[2];
#pragma unroll
        for (int ft = 0; ft < 2; ++ft) {
            const int tr = t0 + wt * 32 + ft * 16 + l15;
#pragma unroll
            for (int kc = 0; kc < 2; ++kc) {
                kh[ft][kc] = *(const s16x8*)(Kh + (size_t)tr * DK + kc * 32 + lg * 8);
                kl[ft][kc] = *(const s16x8*)(Kl + (size_t)tr * DK + kc * 32 + lg * 8);
            }
            k2v[ft] = k2b[tr];
            cv[ft]  = 1.0f / __builtin_amdgcn_sqrtf(NCb[tr]);   // N_C^-0.5
        }
        __syncthreads();   // prev-iter W reads complete before overwrite

#pragma unroll
        for (int fs = 0; fs < 2; ++fs)
#pragma unroll
            for (int ft = 0; ft < 2; ++ft) {
                f32x4 acc = {0.f, 0.f, 0.f, 0.f};
#pragma unroll
                for (int kc = 0; kc < 2; ++kc) {
                    acc = __builtin_amdgcn_mfma_f32_16x16x32_bf16(qh[fs][kc],  kh[ft][kc], acc, 0, 0, 0);
                    acc = __builtin_amdgcn_mfma_f32_16x16x32_bf16(qh[fs][kc],  kl[ft][kc], acc, 0, 0, 0);
                    acc = __builtin_amdgcn_mfma_f32_16x16x32_bf16(qlr[fs][kc], kh[ft][kc], acc, 0, 0, 0);
                }
#pragma unroll
                for (int i = 0; i < 4; ++i) {
                    float d2 = q2v[fs][i] + k2v[ft] - 2.0f * acc[i];
                    float w  = compat_fn(d2) * cv[ft];
                    rowacc[fs][i] += w;
                    unsigned short hb = f2bf(w);
                    unsigned short lb = f2bf(w - bf2f(hb));
                    const int sl = ws * 32 + fs * 16 + lg * 4 + i;
                    const int tl = wt * 32 + ft * 16 + l15;
                    Wh[sl][tl] = hb;
                    Wl[sl][tl] = lb;
                }
            }
        __syncthreads();   // W tile complete

        // PV: wave computes O quadrant (ws, wd=wt); contract over this t-chunk
        s16x8 wh[2][2], wl[2][2];
#pragma unroll
        for (int fs = 0; fs < 2; ++fs) {
            const int sl = ws * 32 + fs * 16 + l15;
#pragma unroll
            for (int kc = 0; kc < 2; ++kc) {
                wh[fs][kc] = *(const s16x8*)&Wh[sl][kc * 32 + lg * 8];
                wl[fs][kc] = *(const s16x8*)&Wl[sl][kc * 32 + lg * 8];
            }
        }
        s16x8 vh[2][2], vl[2][2];
#pragma unroll
        for (int fd = 0; fd < 2; ++fd) {
            const int dr = wt * 32 + fd * 16 + l15;
#pragma unroll
            for (int kc = 0; kc < 2; ++kc) {
                vh[fd][kc] = *(const s16x8*)(Vh + (size_t)dr * S_LEN + t0 + kc * 32 + lg * 8);
                vl[fd][kc] = *(const s16x8*)(Vl + (size_t)dr * S_LEN + t0 + kc * 32 + lg * 8);
            }
        }
#pragma unroll
        for (int fs = 0; fs < 2; ++fs)
#pragma unroll
            for (int fd = 0; fd < 2; ++fd)
#pragma unroll
                for (int kc = 0; kc < 2; ++kc) {
                    o[fs][fd] = __builtin_amdgcn_mfma_f32_16x16x32_bf16(wh[fs][kc], vh[fd][kc], o[fs][fd], 0, 0, 0);
                    o[fs][fd] = __builtin_amdgcn_mfma_f32_16x16x32_bf16(wh[fs][kc], vl[fd][kc], o[fs][fd], 0, 0, 0);
                    o[fs][fd] = __builtin_amdgcn_mfma_f32_16x16x32_bf16(wl[fs][kc], vh[fd][kc], o[fs][fd], 0, 0, 0);
                }
    }

    // row sums: reduce across the 16 column-lanes, then across the two wt waves
#pragma unroll
    for (int fs = 0; fs < 2; ++fs)
#pragma unroll
        for (int i = 0; i < 4; ++i) {
            float r = rowacc[fs][i];
            r += __shfl_xor(r, 1);
            r += __shfl_xor(r, 2);
            r += __shfl_xor(r, 4);
            r += __shfl_xor(r, 8);
            rowacc[fs][i] = r;
        }
    if (l15 == 0) {
#pragma unroll
        for (int fs = 0; fs < 2; ++fs)
#pragma unroll
            for (int i = 0; i < 4; ++i)
                rsum[wt][ws * 32 + fs * 16 + lg * 4 + i] = rowacc[fs][i];
    }
    __syncthreads();

#pragma unroll
    for (int fs = 0; fs < 2; ++fs)
#pragma unroll
        for (int i = 0; i < 4; ++i) {
            const int sl   = ws * 32 + fs * 16 + lg * 4 + i;
            const float inv = 1.0f / (rsum[0][sl] + rsum[1][sl]);
            const int srow = s0 + sl;
#pragma unroll
            for (int fd = 0; fd < 2; ++fd) {
                const int d = wt * 32 + fd * 16 + l15;
                ATTN[((size_t)(b * S_LEN + srow)) * D_MODEL + h * DK + d] = o[fs][fd][i] * inv;
            }
        }
}

extern "C" void kernel_launch(void* const* d_in, const int* in_sizes, int n_in,
                              void* d_out, int out_size, void* d_ws, size_t ws_size,
                              hipStream_t stream) {
    const float* queries = (const float*)d_in[0];
    const float* keys    = (const float*)d_in[1];
    const float* values  = (const float*)d_in[2];
    const float* Wq      = (const float*)d_in[3];
    const float* Wk      = (const float*)d_in[4];
    const float* Wv      = (const float*)d_in[5];
    const float* Wo      = (const float*)d_in[6];
    const float* bo      = (const float*)d_in[7];
    float* out = (float*)d_out;

    const size_t QKV = (size_t)BH * S_LEN * DK;   // 8388608
    unsigned short* Qhi  = (unsigned short*)d_ws;
    unsigned short* Qlo  = Qhi  + QKV;
    unsigned short* Khi  = Qlo  + QKV;
    unsigned short* Klo  = Khi  + QKV;
    unsigned short* VThi = Klo  + QKV;
    unsigned short* VTlo = VThi + QKV;
    float* ATTN = (float*)(VTlo + QKV);           // 33.55 MB
    float* q2   = ATTN + QKV;
    float* k2   = q2 + (size_t)BH * S_LEN;
    float* NC   = k2 + (size_t)BH * S_LEN;

    dim3 blk(16, 16);
    dim3 gproj(D_MODEL / 128, M_ROWS / 128);      // (8, 64)
    proj_gemm<0><<<gproj, blk, 0, stream>>>(queries, Wq, nullptr, nullptr, Qhi, Qlo);
    proj_gemm<0><<<gproj, blk, 0, stream>>>(keys,    Wk, nullptr, nullptr, Khi, Klo);
    proj_gemm<2><<<gproj, blk, 0, stream>>>(values,  Wv, nullptr, nullptr, VThi, VTlo);

    row_norms<<<(2 * BH * S_LEN) / 4, 256, 0, stream>>>(Qhi, Qlo, Khi, Klo, q2, k2);

    dim3 gpass(S_LEN / 64, BH);                   // (32, 64)
    colsum_mfma<<<gpass, 256, 0, stream>>>(Qhi, Qlo, Khi, Klo, q2, k2, NC);
    attn_mfma<<<gpass, 256, 0, stream>>>(Qhi, Qlo, Khi, Klo, VThi, VTlo, q2, k2, NC, ATTN);

    proj_gemm<1><<<gproj, blk, 0, stream>>>(ATTN, Wo, bo, out, nullptr, nullptr);
}

// Round 3
// 1302.304 us; speedup vs baseline: 2.1826x; 1.4641x over previous
//
#include <hip/hip_runtime.h>

#define D_MODEL 1024
#define NHEADS  16
#define DK      64
#define S_LEN   2048
#define BATCH   4
#define BH      (BATCH * NHEADS)     // 64
#define M_ROWS  (BATCH * S_LEN)      // 8192

typedef float  f32x4 __attribute__((ext_vector_type(4)));
typedef short  s16x8 __attribute__((ext_vector_type(8)));
typedef unsigned short u16;
typedef u16 us8 __attribute__((ext_vector_type(8)));

__device__ __forceinline__ u16 f2bf(float f) {
    unsigned u = __builtin_bit_cast(unsigned, f);
    u += 0x7FFFu + ((u >> 16) & 1u);
    return (u16)(u >> 16);
}
__device__ __forceinline__ float bf2f(u16 b) {
    unsigned u = ((unsigned)b) << 16;
    return __builtin_bit_cast(float, u);
}

// compat = (1 + sqrt(max(d2,0))/64)^(-65) = exp2(-65 * log2(p))
__device__ __forceinline__ float compat_fn(float d2) {
    float g = __builtin_amdgcn_sqrtf(fmaxf(d2, 0.0f)) * 0.015625f;
    float p = 1.0f + g;
    return __builtin_amdgcn_exp2f(-65.0f * __builtin_amdgcn_logf(p));
}

__device__ __forceinline__ void gll16(const void* g, void* l) {
    __builtin_amdgcn_global_load_lds(
        (const __attribute__((address_space(1))) void*)g,
        (__attribute__((address_space(3))) void*)l, 16, 0, 0);
}

#define MFMA_BF16(a, b, c) __builtin_amdgcn_mfma_f32_16x16x32_bf16(a, b, c, 0, 0, 0)

// fp32 -> (hi, lo) bf16 split, 8 elements per thread
__global__ __launch_bounds__(256) void split_bf16(const float* __restrict__ in,
                                                  u16* __restrict__ hi,
                                                  u16* __restrict__ lo, int n8) {
    int i = blockIdx.x * 256 + threadIdx.x;
    if (i >= n8) return;
    const float4* p = (const float4*)in;
    float4 a = p[i * 2], b = p[i * 2 + 1];
    float v[8] = {a.x, a.y, a.z, a.w, b.x, b.y, b.z, b.w};
    us8 h, l;
#pragma unroll
    for (int j = 0; j < 8; ++j) {
        u16 hb = f2bf(v[j]);
        h[j] = hb;
        l[j] = f2bf(v[j] - bf2f(hb));
    }
    ((us8*)hi)[i] = h;
    ((us8*)lo)[i] = l;
}

// Split-bf16 MFMA GEMM: out = A @ B^T (+bias), A[M][1024] hi/lo, B[1024][1024] hi/lo.
// 128x128 tile, BK=64, 4 waves (2x2), 64x64 out/wave, 3-MFMA split accumulate.
// MODE 0: head-split hi/lo bf16  dst[((b*16+h)*2048+s)*64+d]
// MODE 2: head-split TRANSPOSED hi/lo bf16 dst[((b*16+h)*64+d)*2048+t] (for V)
// MODE 1: fp32 outf[m*1024+n] = acc + bias[n]
template <int MODE>
__global__ __launch_bounds__(256, 2) void proj_mfma(
    const u16* __restrict__ Ah, const u16* __restrict__ Al,
    const u16* __restrict__ Bh, const u16* __restrict__ Bl,
    const float* __restrict__ bias,
    float* __restrict__ outf, u16* __restrict__ ohi, u16* __restrict__ olo) {
    __shared__ __align__(16) u16 lds[4 * 128 * 64];   // 64 KB: Ah|Al|Bh|Bl tiles
    u16* LAh = lds;
    u16* LAl = lds + 8192;
    u16* LBh = lds + 16384;
    u16* LBl = lds + 24576;

    const int tid  = threadIdx.x;
    const int wave = tid >> 6, lane = tid & 63;
    const int wm = wave >> 1, wn = wave & 1;
    const int l15 = lane & 15, lg = lane >> 4;
    const int n0 = blockIdx.x * 128;
    const int m0 = blockIdx.y * 128;

    // staging geometry: element e = wave*2048 + q*512 + lane*8 -> row e>>6, col e&63
    const int srow = wave * 32 + (lane >> 3);
    const int scol = (lane & 7) * 8;

    f32x4 acc[4][4];
#pragma unroll
    for (int i = 0; i < 4; ++i)
#pragma unroll
        for (int j = 0; j < 4; ++j) acc[i][j] = (f32x4){0.f, 0.f, 0.f, 0.f};

#pragma unroll 1
    for (int k0 = 0; k0 < D_MODEL; k0 += 64) {
        __syncthreads();   // previous compute done before overwrite
#pragma unroll
        for (int q = 0; q < 4; ++q) {
            const size_t ga = (size_t)(m0 + srow + q * 8) * D_MODEL + k0 + scol;
            const size_t gb = (size_t)(n0 + srow + q * 8) * D_MODEL + k0 + scol;
            u16* ldst = (u16*)lds + wave * 2048 + q * 512;   // +lane*8 implicit
            gll16(Ah + ga, LAh + wave * 2048 + q * 512);
            gll16(Al + ga, LAl + wave * 2048 + q * 512);
            gll16(Bh + gb, LBh + wave * 2048 + q * 512);
            gll16(Bl + gb, LBl + wave * 2048 + q * 512);
            (void)ldst;
        }
        __syncthreads();   // staged data visible (compiler drains vmcnt before barrier)
#pragma unroll
        for (int kc = 0; kc < 2; ++kc) {
            s16x8 ah[4], al[4];
#pragma unroll
            for (int fm = 0; fm < 4; ++fm) {
                const int r = wm * 64 + fm * 16 + l15;
                ah[fm] = *(const s16x8*)&LAh[r * 64 + kc * 32 + lg * 8];
                al[fm] = *(const s16x8*)&LAl[r * 64 + kc * 32 + lg * 8];
            }
#pragma unroll
            for (int fn = 0; fn < 4; ++fn) {
                const int r = wn * 64 + fn * 16 + l15;
                s16x8 bh = *(const s16x8*)&LBh[r * 64 + kc * 32 + lg * 8];
                s16x8 bl = *(const s16x8*)&LBl[r * 64 + kc * 32 + lg * 8];
#pragma unroll
                for (int fm = 0; fm < 4; ++fm) {
                    acc[fm][fn] = MFMA_BF16(ah[fm], bh, acc[fm][fn]);
                    acc[fm][fn] = MFMA_BF16(ah[fm], bl, acc[fm][fn]);
                    acc[fm][fn] = MFMA_BF16(al[fm], bh, acc[fm][fn]);
                }
            }
        }
    }
    __syncthreads();   // LDS free for epilogue reuse

    if (MODE == 0) {
        const int h = (n0 >> 6) + wn;   // n0 multiple of 128 -> h = n/64
#pragma unroll
        for (int fm = 0; fm < 4; ++fm)
#pragma unroll
            for (int i = 0; i < 4; ++i) {
                const int m = m0 + wm * 64 + fm * 16 + lg * 4 + i;
                const int b = m >> 11, s = m & 2047;
                const size_t rb = ((size_t)((b * NHEADS + h) * S_LEN + s)) * DK;
#pragma unroll
                for (int fn = 0; fn < 4; ++fn) {
                    float v = acc[fm][fn][i];
                    u16 hb = f2bf(v);
                    u16 lb = f2bf(v - bf2f(hb));
                    ohi[rb + fn * 16 + l15] = hb;
                    olo[rb + fn * 16 + l15] = lb;
                }
            }
    } else if (MODE == 1) {
#pragma unroll
        for (int fm = 0; fm < 4; ++fm)
#pragma unroll
            for (int i = 0; i < 4; ++i) {
                const int m = m0 + wm * 64 + fm * 16 + lg * 4 + i;
#pragma unroll
                for (int fn = 0; fn < 4; ++fn) {
                    const int n = n0 + wn * 64 + fn * 16 + l15;
                    outf[(size_t)m * D_MODEL + n] = acc[fm][fn][i] + bias[n];
                }
            }
    } else {   // MODE 2: transpose per-wave 64x64 via LDS, write VT[bh][d][t]
        const int h  = (n0 >> 6) + wn;
        const int b  = m0 >> 11;
        const int bh = b * NHEADS + h;
        const int t_base = (m0 & 2047) + wm * 64;
        u16* T = lds + wave * 4096;   // 8KB per wave, [64][64] = [d_local][t_local]
#pragma unroll
        for (int part = 0; part < 2; ++part) {
#pragma unroll
            for (int fm = 0; fm < 4; ++fm)
#pragma unroll
                for (int fn = 0; fn < 4; ++fn)
#pragma unroll
                    for (int i = 0; i < 4; ++i) {
                        float v = acc[fm][fn][i];
                        u16 hb = f2bf(v);
                        u16 u = (part == 0) ? hb : f2bf(v - bf2f(hb));
                        T[(fn * 16 + l15) * 64 + fm * 16 + lg * 4 + i] = u;
                    }
            __syncthreads();
            u16* dst = (part == 0) ? ohi : olo;
#pragma unroll
            for (int j = 0; j < 8; ++j) {
                const int cid = j * 64 + lane;       // 0..511
                const int dr = cid >> 3;             // 0..63
                const int cc = (cid & 7) * 8;
                us8 v8 = *(const us8*)&T[dr * 64 + cc];
                *(us8*)&dst[((size_t)(bh * DK + dr)) * S_LEN + t_base + cc] = v8;
            }
            __syncthreads();
        }
    }
}

// squared L2 norms of Q rows and K rows from hi+lo bf16; one wave per row
__global__ __launch_bounds__(256) void row_norms(const u16* __restrict__ Qhi,
                                                 const u16* __restrict__ Qlo,
                                                 const u16* __restrict__ Khi,
                                                 const u16* __restrict__ Klo,
                                                 float* __restrict__ q2,
                                                 float* __restrict__ k2) {
    int wid  = blockIdx.x * 4 + (threadIdx.x >> 6);
    int lane = threadIdx.x & 63;
    const u16 *hi, *lo; float* dstp; int row;
    if (wid < BH * S_LEN) { hi = Qhi; lo = Qlo; dstp = q2; row = wid; }
    else                  { hi = Khi; lo = Klo; dstp = k2; row = wid - BH * S_LEN; }
    float v = bf2f(hi[(size_t)row * DK + lane]) + bf2f(lo[(size_t)row * DK + lane]);
    float s = v * v;
#pragma unroll
    for (int off = 32; off > 0; off >>= 1) s += __shfl_xor(s, off);
    if (lane == 0) dstp[row] = s;
}

// Pass A (MFMA): column sums NC[t] = sum_s compat[s,t].
__global__ __launch_bounds__(256, 4) void colsum_mfma(
    const u16* __restrict__ Qhi, const u16* __restrict__ Qlo,
    const u16* __restrict__ Khi, const u16* __restrict__ Klo,
    const float* __restrict__ q2, const float* __restrict__ k2,
    float* __restrict__ NC) {
    const int tid  = threadIdx.x;
    const int wave = tid >> 6, lane = tid & 63;
    const int ws = wave >> 1, wt = wave & 1;
    const int l15 = lane & 15, lg = lane >> 4;
    const int bh = blockIdx.y;
    const int t0 = blockIdx.x * 64;
    const size_t base = (size_t)bh * S_LEN * DK;
    const u16* Kh = Khi + base;
    const u16* Kl = Klo + base;
    const u16* Qh = Qhi + base;
    const u16* Ql = Qlo + base;
    const float* q2b = q2 + (size_t)bh * S_LEN;
    const float* k2b = k2 + (size_t)bh * S_LEN;

    s16x8 kh[2][2], kl[2][2];
    float k2v[2];
#pragma unroll
    for (int ft = 0; ft < 2; ++ft) {
        const int tr = t0 + wt * 32 + ft * 16 + l15;
#pragma unroll
        for (int kc = 0; kc < 2; ++kc) {
            kh[ft][kc] = *(const s16x8*)(Kh + (size_t)tr * DK + kc * 32 + lg * 8);
            kl[ft][kc] = *(const s16x8*)(Kl + (size_t)tr * DK + kc * 32 + lg * 8);
        }
        k2v[ft] = k2b[tr];
    }
    float colacc[2] = {0.f, 0.f};

    for (int s0 = 0; s0 < S_LEN; s0 += 64) {
        const int sb = s0 + ws * 32;
        s16x8 qh[2][2], ql[2][2];
#pragma unroll
        for (int fs = 0; fs < 2; ++fs) {
            const int qr = sb + fs * 16 + l15;
#pragma unroll
            for (int kc = 0; kc < 2; ++kc) {
                qh[fs][kc] = *(const s16x8*)(Qh + (size_t)qr * DK + kc * 32 + lg * 8);
                ql[fs][kc] = *(const s16x8*)(Ql + (size_t)qr * DK + kc * 32 + lg * 8);
            }
        }
        float q2v[2][4];
#pragma unroll
        for (int fs = 0; fs < 2; ++fs)
#pragma unroll
            for (int i = 0; i < 4; ++i)
                q2v[fs][i] = q2b[sb + fs * 16 + lg * 4 + i];

#pragma unroll
        for (int fs = 0; fs < 2; ++fs)
#pragma unroll
            for (int ft = 0; ft < 2; ++ft) {
                f32x4 acc = {0.f, 0.f, 0.f, 0.f};
#pragma unroll
                for (int kc = 0; kc < 2; ++kc) {
                    acc = MFMA_BF16(qh[fs][kc], kh[ft][kc], acc);
                    acc = MFMA_BF16(qh[fs][kc], kl[ft][kc], acc);
                    acc = MFMA_BF16(ql[fs][kc], kh[ft][kc], acc);
                }
#pragma unroll
                for (int i = 0; i < 4; ++i) {
                    float d2 = q2v[fs][i] + k2v[ft] - 2.0f * acc[i];
                    colacc[ft] += compat_fn(d2);
                }
            }
    }
#pragma unroll
    for (int ft = 0; ft < 2; ++ft) {
        colacc[ft] += __shfl_xor(colacc[ft], 16);
        colacc[ft] += __shfl_xor(colacc[ft], 32);
    }
    __shared__ float cs[4][64];
    if (lg == 0) {
        cs[wave][wt * 32 + l15]      = colacc[0];
        cs[wave][wt * 32 + 16 + l15] = colacc[1];
    }
    __syncthreads();
    if (tid < 64) {
        int wtj = tid >> 5;
        NC[(size_t)bh * S_LEN + t0 + tid] = cs[wtj][tid] + cs[wtj + 2][tid];
    }
}

// Pass B (MFMA, flash-style); writes ATTN as hi/lo bf16 merged [m][1024]
__global__ __launch_bounds__(256, 4) void attn_mfma(
    const u16* __restrict__ Qhi, const u16* __restrict__ Qlo,
    const u16* __restrict__ Khi, const u16* __restrict__ Klo,
    const u16* __restrict__ VThi, const u16* __restrict__ VTlo,
    const float* __restrict__ q2, const float* __restrict__ k2,
    const float* __restrict__ NC,
    u16* __restrict__ ATTNhi, u16* __restrict__ ATTNlo) {
    __shared__ __align__(16) u16 Wh[64][72];   // [s][t], 144B rows
    __shared__ __align__(16) u16 Wl[64][72];
    __shared__ float rsum[2][64];
    const int tid  = threadIdx.x;
    const int wave = tid >> 6, lane = tid & 63;
    const int ws = wave >> 1, wt = wave & 1;
    const int l15 = lane & 15, lg = lane >> 4;
    const int bh = blockIdx.y;
    const int s0 = blockIdx.x * 64;
    const int b = bh >> 4, h = bh & 15;
    const size_t base = (size_t)bh * S_LEN * DK;
    const u16* Qh = Qhi + base;
    const u16* Ql = Qlo + base;
    const u16* Kh = Khi + base;
    const u16* Kl = Klo + base;
    const u16* Vh = VThi + base;   // per-bh [64][2048]
    const u16* Vl = VTlo + base;
    const float* q2b = q2 + (size_t)bh * S_LEN;
    const float* k2b = k2 + (size_t)bh * S_LEN;
    const float* NCb = NC + (size_t)bh * S_LEN;

    s16x8 qh[2][2], qlr[2][2];
#pragma unroll
    for (int fs = 0; fs < 2; ++fs) {
        const int qr = s0 + ws * 32 + fs * 16 + l15;
#pragma unroll
        for (int kc = 0; kc < 2; ++kc) {
            qh[fs][kc]  = *(const s16x8*)(Qh + (size_t)qr * DK + kc * 32 + lg * 8);
            qlr[fs][kc] = *(const s16x8*)(Ql + (size_t)qr * DK + kc * 32 + lg * 8);
        }
    }
    float q2v[2][4];
#pragma unroll
    for (int fs = 0; fs < 2; ++fs)
#pragma unroll
        for (int i = 0; i < 4; ++i)
            q2v[fs][i] = q2b[s0 + ws * 32 + fs * 16 + lg * 4 + i];

    f32x4 o[2][2];
#pragma unroll
    for (int fs = 0; fs < 2; ++fs)
#pragma unroll
        for (int fd = 0; fd < 2; ++fd)
            o[fs][fd] = (f32x4){0.f, 0.f, 0.f, 0.f};
    float rowacc[2][4] = {};

    for (int t0 = 0; t0 < S_LEN; t0 += 64) {
        s16x8 kh[2][2], kl[2][2];
        float k2v[2], cv[2];
#pragma unroll
        for (int ft = 0; ft < 2; ++ft) {
            const int tr = t0 + wt * 32 + ft * 16 + l15;
#pragma unroll
            for (int kc = 0; kc < 2; ++kc) {
                kh[ft][kc] = *(const s16x8*)(Kh + (size_t)tr * DK + kc * 32 + lg * 8);
                kl[ft][kc] = *(const s16x8*)(Kl + (size_t)tr * DK + kc * 32 + lg * 8);
            }
            k2v[ft] = k2b[tr];
            cv[ft]  = 1.0f / __builtin_amdgcn_sqrtf(NCb[tr]);
        }
        __syncthreads();   // prev-iter W reads complete before overwrite

#pragma unroll
        for (int fs = 0; fs < 2; ++fs)
#pragma unroll
            for (int ft = 0; ft < 2; ++ft) {
                f32x4 acc = {0.f, 0.f, 0.f, 0.f};
#pragma unroll
                for (int kc = 0; kc < 2; ++kc) {
                    acc = MFMA_BF16(qh[fs][kc],  kh[ft][kc], acc);
                    acc = MFMA_BF16(qh[fs][kc],  kl[ft][kc], acc);
                    acc = MFMA_BF16(qlr[fs][kc], kh[ft][kc], acc);
                }
#pragma unroll
                for (int i = 0; i < 4; ++i) {
                    float d2 = q2v[fs][i] + k2v[ft] - 2.0f * acc[i];
                    float w  = compat_fn(d2) * cv[ft];
                    rowacc[fs][i] += w;
                    u16 hb = f2bf(w);
                    u16 lb = f2bf(w - bf2f(hb));
                    const int sl = ws * 32 + fs * 16 + lg * 4 + i;
                    const int tl = wt * 32 + ft * 16 + l15;
                    Wh[sl][tl] = hb;
                    Wl[sl][tl] = lb;
                }
            }
        __syncthreads();   // W tile complete

        s16x8 wh[2][2], wl[2][2];
#pragma unroll
        for (int fs = 0; fs < 2; ++fs) {
            const int sl = ws * 32 + fs * 16 + l15;
#pragma unroll
            for (int kc = 0; kc < 2; ++kc) {
                wh[fs][kc] = *(const s16x8*)&Wh[sl][kc * 32 + lg * 8];
                wl[fs][kc] = *(const s16x8*)&Wl[sl][kc * 32 + lg * 8];
            }
        }
        s16x8 vh[2][2], vl[2][2];
#pragma unroll
        for (int fd = 0; fd < 2; ++fd) {
            const int dr = wt * 32 + fd * 16 + l15;
#pragma unroll
            for (int kc = 0; kc < 2; ++kc) {
                vh[fd][kc] = *(const s16x8*)(Vh + (size_t)dr * S_LEN + t0 + kc * 32 + lg * 8);
                vl[fd][kc] = *(const s16x8*)(Vl + (size_t)dr * S_LEN + t0 + kc * 32 + lg * 8);
            }
        }
#pragma unroll
        for (int fs = 0; fs < 2; ++fs)
#pragma unroll
            for (int fd = 0; fd < 2; ++fd)
#pragma unroll
                for (int kc = 0; kc < 2; ++kc) {
                    o[fs][fd] = MFMA_BF16(wh[fs][kc], vh[fd][kc], o[fs][fd]);
                    o[fs][fd] = MFMA_BF16(wh[fs][kc], vl[fd][kc], o[fs][fd]);
                    o[fs][fd] = MFMA_BF16(wl[fs][kc], vh[fd][kc], o[fs][fd]);
                }
    }

#pragma unroll
    for (int fs = 0; fs < 2; ++fs)
#pragma unroll
        for (int i = 0; i < 4; ++i) {
            float r = rowacc[fs][i];
            r += __shfl_xor(r, 1);
            r += __shfl_xor(r, 2);
            r += __shfl_xor(r, 4);
            r += __shfl_xor(r, 8);
            rowacc[fs][i] = r;
        }
    if (l15 == 0) {
#pragma unroll
        for (int fs = 0; fs < 2; ++fs)
#pragma unroll
            for (int i = 0; i < 4; ++i)
                rsum[wt][ws * 32 + fs * 16 + lg * 4 + i] = rowacc[fs][i];
    }
    __syncthreads();

#pragma unroll
    for (int fs = 0; fs < 2; ++fs)
#pragma unroll
        for (int i = 0; i < 4; ++i) {
            const int sl   = ws * 32 + fs * 16 + lg * 4 + i;
            const float inv = 1.0f / (rsum[0][sl] + rsum[1][sl]);
            const int srow = s0 + sl;
#pragma unroll
            for (int fd = 0; fd < 2; ++fd) {
                const int d = wt * 32 + fd * 16 + l15;
                float v = o[fs][fd][i] * inv;
                u16 hb = f2bf(v);
                u16 lb = f2bf(v - bf2f(hb));
                size_t idx = ((size_t)(b * S_LEN + srow)) * D_MODEL + h * DK + d;
                ATTNhi[idx] = hb;
                ATTNlo[idx] = lb;
            }
        }
}

extern "C" void kernel_launch(void* const* d_in, const int* in_sizes, int n_in,
                              void* d_out, int out_size, void* d_ws, size_t ws_size,
                              hipStream_t stream) {
    const float* queries = (const float*)d_in[0];
    const float* keys    = (const float*)d_in[1];
    const float* values  = (const float*)d_in[2];
    const float* Wq      = (const float*)d_in[3];
    const float* Wk      = (const float*)d_in[4];
    const float* Wv      = (const float*)d_in[5];
    const float* Wo      = (const float*)d_in[6];
    const float* bo      = (const float*)d_in[7];
    float* out = (float*)d_out;

    const size_t NW = (size_t)D_MODEL * D_MODEL;     // 1,048,576
    const size_t NX = (size_t)M_ROWS * D_MODEL;      // 8,388,608
    u16* base = (u16*)d_ws;
    size_t off = 0;
    auto take = [&](size_t n) { u16* r = base + off; off += n; return r; };
    u16 *Wqh = take(NW), *Wql = take(NW), *Wkh = take(NW), *Wkl = take(NW);
    u16 *Wvh = take(NW), *Wvl = take(NW), *Woh = take(NW), *Wol = take(NW);
    u16 *Xqh = take(NX), *Xql = take(NX);
    u16 *Xkh = take(NX), *Xkl = take(NX);
    u16 *Xvh = take(NX), *Xvl = take(NX);
    u16 *Qhi = take(NX), *Qlo = take(NX), *Khi = take(NX), *Klo = take(NX);
    u16 *VThi = take(NX), *VTlo = take(NX);
    // reuse regions that are dead by the time these are written:
    u16* ATTNhi = Xqh;                 // dead after Q projection
    u16* ATTNlo = Xql;
    float* q2 = (float*)Xkh;           // dead after K projection
    float* k2 = q2 + (size_t)BH * S_LEN;
    float* NC = k2 + (size_t)BH * S_LEN;

    // 1) split inputs and weights into hi/lo bf16
    split_bf16<<<(int)(NX / 8 / 256), 256, 0, stream>>>(queries, Xqh, Xql, (int)(NX / 8));
    split_bf16<<<(int)(NX / 8 / 256), 256, 0, stream>>>(keys,    Xkh, Xkl, (int)(NX / 8));
    split_bf16<<<(int)(NX / 8 / 256), 256, 0, stream>>>(values,  Xvh, Xvl, (int)(NX / 8));
    split_bf16<<<(int)(NW / 8 / 256), 256, 0, stream>>>(Wq, Wqh, Wql, (int)(NW / 8));
    split_bf16<<<(int)(NW / 8 / 256), 256, 0, stream>>>(Wk, Wkh, Wkl, (int)(NW / 8));
    split_bf16<<<(int)(NW / 8 / 256), 256, 0, stream>>>(Wv, Wvh, Wvl, (int)(NW / 8));
    split_bf16<<<(int)(NW / 8 / 256), 256, 0, stream>>>(Wo, Woh, Wol, (int)(NW / 8));

    // 2) projections (MFMA split-bf16)
    dim3 gproj(D_MODEL / 128, M_ROWS / 128);   // (8, 64)
    proj_mfma<0><<<gproj, 256, 0, stream>>>(Xqh, Xql, Wqh, Wql, nullptr, nullptr, Qhi, Qlo);
    proj_mfma<0><<<gproj, 256, 0, stream>>>(Xkh, Xkl, Wkh, Wkl, nullptr, nullptr, Khi, Klo);
    proj_mfma<2><<<gproj, 256, 0, stream>>>(Xvh, Xvl, Wvh, Wvl, nullptr, nullptr, VThi, VTlo);

    // 3) row norms
    row_norms<<<(2 * BH * S_LEN) / 4, 256, 0, stream>>>(Qhi, Qlo, Khi, Klo, q2, k2);

    // 4) column sums, then flash-style attention
    dim3 gpass(S_LEN / 64, BH);                // (32, 64)
    colsum_mfma<<<gpass, 256, 0, stream>>>(Qhi, Qlo, Khi, Klo, q2, k2, NC);
    attn_mfma<<<gpass, 256, 0, stream>>>(Qhi, Qlo, Khi, Klo, VThi, VTlo, q2, k2, NC, ATTNhi, ATTNlo);

    // 5) output projection + bias (MFMA split-bf16, fp32 out)
    proj_mfma<1><<<gproj, 256, 0, stream>>>(ATTNhi, ATTNlo, Woh, Wol, bo, out, nullptr, nullptr);
}

// Round 4
// 895.842 us; speedup vs baseline: 3.1729x; 1.4537x over previous
//
#include <hip/hip_runtime.h>

#define D_MODEL 1024
#define NHEADS  16
#define DK      64
#define S_LEN   2048
#define BATCH   4
#define BH      (BATCH * NHEADS)     // 64
#define M_ROWS  (BATCH * S_LEN)      // 8192

typedef float  f32x4 __attribute__((ext_vector_type(4)));
typedef short  s16x8 __attribute__((ext_vector_type(8)));
typedef unsigned short u16;
typedef u16 us8 __attribute__((ext_vector_type(8)));

__device__ __forceinline__ u16 f2bf(float f) {
    unsigned u = __builtin_bit_cast(unsigned, f);
    u += 0x7FFFu + ((u >> 16) & 1u);
    return (u16)(u >> 16);
}
__device__ __forceinline__ float bf2f(u16 b) {
    unsigned u = ((unsigned)b) << 16;
    return __builtin_bit_cast(float, u);
}

// compat = (1 + sqrt(max(d2,0))/64)^(-65) = exp2(-65 * log2(p))
__device__ __forceinline__ float compat_fn(float d2) {
    float g = __builtin_amdgcn_sqrtf(fmaxf(d2, 0.0f)) * 0.015625f;
    float p = 1.0f + g;
    return __builtin_amdgcn_exp2f(-65.0f * __builtin_amdgcn_logf(p));
}

__device__ __forceinline__ void gll16(const void* g, void* l) {
    __builtin_amdgcn_global_load_lds(
        (const __attribute__((address_space(1))) void*)g,
        (__attribute__((address_space(3))) void*)l, 16, 0, 0);
}

#define MFMA_BF16(a, b, c) __builtin_amdgcn_mfma_f32_16x16x32_bf16(a, b, c, 0, 0, 0)

// fp32 -> (hi, lo) bf16 split, 8 elements per thread
__global__ __launch_bounds__(256) void split_bf16(const float* __restrict__ in,
                                                  u16* __restrict__ hi,
                                                  u16* __restrict__ lo, int n8) {
    int i = blockIdx.x * 256 + threadIdx.x;
    if (i >= n8) return;
    const float4* p = (const float4*)in;
    float4 a = p[i * 2], b = p[i * 2 + 1];
    float v[8] = {a.x, a.y, a.z, a.w, b.x, b.y, b.z, b.w};
    us8 h, l;
#pragma unroll
    for (int j = 0; j < 8; ++j) {
        u16 hb = f2bf(v[j]);
        h[j] = hb;
        l[j] = f2bf(v[j] - bf2f(hb));
    }
    ((us8*)hi)[i] = h;
    ((us8*)lo)[i] = l;
}

// Split-bf16 MFMA GEMM: out = A @ B^T (+bias).
// MODE 0: head-split hi/lo bf16  dst[((b*16+h)*2048+s)*64+d]
// MODE 2: head-split TRANSPOSED bf16 (HI ONLY) dst[((b*16+h)*64+d)*2048+t]
// MODE 1: fp32 outf[m*1024+n] = acc + bias[n]
template <int MODE>
__global__ __launch_bounds__(256, 2) void proj_mfma(
    const u16* __restrict__ Ah, const u16* __restrict__ Al,
    const u16* __restrict__ Bh, const u16* __restrict__ Bl,
    const float* __restrict__ bias,
    float* __restrict__ outf, u16* __restrict__ ohi, u16* __restrict__ olo) {
    __shared__ __align__(16) u16 lds[4 * 128 * 64];   // 64 KB
    u16* LAh = lds;
    u16* LAl = lds + 8192;
    u16* LBh = lds + 16384;
    u16* LBl = lds + 24576;

    const int tid  = threadIdx.x;
    const int wave = tid >> 6, lane = tid & 63;
    const int wm = wave >> 1, wn = wave & 1;
    const int l15 = lane & 15, lg = lane >> 4;
    // XCD swizzle: 512 blocks, 64 per XCD chunk
    const int flat = blockIdx.y * 8 + blockIdx.x;
    const int swz  = (flat & 7) * 64 + (flat >> 3);
    const int n0 = (swz & 7) * 128;
    const int m0 = (swz >> 3) * 128;

    const int srow = wave * 32 + (lane >> 3);
    const int scol = (lane & 7) * 8;

    f32x4 acc[4][4];
#pragma unroll
    for (int i = 0; i < 4; ++i)
#pragma unroll
        for (int j = 0; j < 4; ++j) acc[i][j] = (f32x4){0.f, 0.f, 0.f, 0.f};

#pragma unroll 1
    for (int k0 = 0; k0 < D_MODEL; k0 += 64) {
        __syncthreads();
#pragma unroll
        for (int q = 0; q < 4; ++q) {
            const size_t ga = (size_t)(m0 + srow + q * 8) * D_MODEL + k0 + scol;
            const size_t gb = (size_t)(n0 + srow + q * 8) * D_MODEL + k0 + scol;
            gll16(Ah + ga, LAh + wave * 2048 + q * 512);
            gll16(Al + ga, LAl + wave * 2048 + q * 512);
            gll16(Bh + gb, LBh + wave * 2048 + q * 512);
            gll16(Bl + gb, LBl + wave * 2048 + q * 512);
        }
        __syncthreads();
#pragma unroll
        for (int kc = 0; kc < 2; ++kc) {
            s16x8 ah[4], al[4];
#pragma unroll
            for (int fm = 0; fm < 4; ++fm) {
                const int r = wm * 64 + fm * 16 + l15;
                ah[fm] = *(const s16x8*)&LAh[r * 64 + kc * 32 + lg * 8];
                al[fm] = *(const s16x8*)&LAl[r * 64 + kc * 32 + lg * 8];
            }
#pragma unroll
            for (int fn = 0; fn < 4; ++fn) {
                const int r = wn * 64 + fn * 16 + l15;
                s16x8 bh = *(const s16x8*)&LBh[r * 64 + kc * 32 + lg * 8];
                s16x8 bl = *(const s16x8*)&LBl[r * 64 + kc * 32 + lg * 8];
#pragma unroll
                for (int fm = 0; fm < 4; ++fm) {
                    acc[fm][fn] = MFMA_BF16(ah[fm], bh, acc[fm][fn]);
                    acc[fm][fn] = MFMA_BF16(ah[fm], bl, acc[fm][fn]);
                    acc[fm][fn] = MFMA_BF16(al[fm], bh, acc[fm][fn]);
                }
            }
        }
    }
    __syncthreads();   // LDS free for epilogue reuse

    if (MODE == 0) {
        const int h = (n0 >> 6) + wn;
#pragma unroll
        for (int fm = 0; fm < 4; ++fm)
#pragma unroll
            for (int i = 0; i < 4; ++i) {
                const int m = m0 + wm * 64 + fm * 16 + lg * 4 + i;
                const int b = m >> 11, s = m & 2047;
                const size_t rb = ((size_t)((b * NHEADS + h) * S_LEN + s)) * DK;
#pragma unroll
                for (int fn = 0; fn < 4; ++fn) {
                    float v = acc[fm][fn][i];
                    u16 hb = f2bf(v);
                    u16 lb = f2bf(v - bf2f(hb));
                    ohi[rb + fn * 16 + l15] = hb;
                    olo[rb + fn * 16 + l15] = lb;
                }
            }
    } else if (MODE == 1) {
#pragma unroll
        for (int fm = 0; fm < 4; ++fm)
#pragma unroll
            for (int i = 0; i < 4; ++i) {
                const int m = m0 + wm * 64 + fm * 16 + lg * 4 + i;
#pragma unroll
                for (int fn = 0; fn < 4; ++fn) {
                    const int n = n0 + wn * 64 + fn * 16 + l15;
                    outf[(size_t)m * D_MODEL + n] = acc[fm][fn][i] + bias[n];
                }
            }
    } else {   // MODE 2: per-wave 64x64 transpose, HI only -> VT[bh][d][t]
        const int h  = (n0 >> 6) + wn;
        const int b  = m0 >> 11;
        const int bh = b * NHEADS + h;
        const int t_base = (m0 & 2047) + wm * 64;
        u16* T = lds + wave * 4096;   // [64][64] = [d_local][t_local]
#pragma unroll
        for (int fm = 0; fm < 4; ++fm)
#pragma unroll
            for (int fn = 0; fn < 4; ++fn)
#pragma unroll
                for (int i = 0; i < 4; ++i)
                    T[(fn * 16 + l15) * 64 + fm * 16 + lg * 4 + i] = f2bf(acc[fm][fn][i]);
        __syncthreads();
#pragma unroll
        for (int j = 0; j < 8; ++j) {
            const int cid = j * 64 + lane;
            const int dr = cid >> 3;
            const int cc = (cid & 7) * 8;
            us8 v8 = *(const us8*)&T[dr * 64 + cc];
            *(us8*)&ohi[((size_t)(bh * DK + dr)) * S_LEN + t_base + cc] = v8;
        }
    }
}

// squared L2 norms of Q rows and K rows from hi+lo bf16; one wave per row
__global__ __launch_bounds__(256) void row_norms(const u16* __restrict__ Qhi,
                                                 const u16* __restrict__ Qlo,
                                                 const u16* __restrict__ Khi,
                                                 const u16* __restrict__ Klo,
                                                 float* __restrict__ q2,
                                                 float* __restrict__ k2) {
    int wid  = blockIdx.x * 4 + (threadIdx.x >> 6);
    int lane = threadIdx.x & 63;
    const u16 *hi, *lo; float* dstp; int row;
    if (wid < BH * S_LEN) { hi = Qhi; lo = Qlo; dstp = q2; row = wid; }
    else                  { hi = Khi; lo = Klo; dstp = k2; row = wid - BH * S_LEN; }
    float v = bf2f(hi[(size_t)row * DK + lane]) + bf2f(lo[(size_t)row * DK + lane]);
    float s = v * v;
#pragma unroll
    for (int off = 32; off > 0; off >>= 1) s += __shfl_xor(s, off);
    if (lane == 0) dstp[row] = s;
}

// Pass A: column sums -> CV[t] = NC[t]^-0.5. Single-bf16 QK (errors average
// over 2048-term column sums). Q-tile prefetched one iter ahead; XCD swizzle.
__global__ __launch_bounds__(256, 4) void colsum_mfma(
    const u16* __restrict__ Qhi, const u16* __restrict__ Khi,
    const float* __restrict__ q2, const float* __restrict__ k2,
    float* __restrict__ CV) {
    const int tid  = threadIdx.x;
    const int wave = tid >> 6, lane = tid & 63;
    const int ws = wave >> 1, wt = wave & 1;
    const int l15 = lane & 15, lg = lane >> 4;
    const int flat = blockIdx.y * 32 + blockIdx.x;
    const int swz  = (flat & 7) * 256 + (flat >> 3);
    const int bh = swz >> 5;
    const int t0 = (swz & 31) * 64;
    const size_t base = (size_t)bh * S_LEN * DK;
    const u16* Kh = Khi + base;
    const u16* Qh = Qhi + base;
    const float* q2b = q2 + (size_t)bh * S_LEN;
    const float* k2b = k2 + (size_t)bh * S_LEN;

    s16x8 kh[2][2];
    float k2v[2];
#pragma unroll
    for (int ft = 0; ft < 2; ++ft) {
        const int tr = t0 + wt * 32 + ft * 16 + l15;
#pragma unroll
        for (int kc = 0; kc < 2; ++kc)
            kh[ft][kc] = *(const s16x8*)(Kh + (size_t)tr * DK + kc * 32 + lg * 8);
        k2v[ft] = k2b[tr];
    }

    s16x8 qh[2][2];
    auto loadQ = [&](int sb) {
#pragma unroll
        for (int fs = 0; fs < 2; ++fs) {
            const int qr = sb + fs * 16 + l15;
#pragma unroll
            for (int kc = 0; kc < 2; ++kc)
                qh[fs][kc] = *(const s16x8*)(Qh + (size_t)qr * DK + kc * 32 + lg * 8);
        }
    };
    loadQ(ws * 32);

    float colacc[2] = {0.f, 0.f};

#pragma unroll 1
    for (int s0 = 0; s0 < S_LEN; s0 += 64) {
        const int sb = s0 + ws * 32;
        float q2v[2][4];
#pragma unroll
        for (int fs = 0; fs < 2; ++fs)
#pragma unroll
            for (int i = 0; i < 4; ++i)
                q2v[fs][i] = q2b[sb + fs * 16 + lg * 4 + i];

        f32x4 acc[2][2];
#pragma unroll
        for (int fs = 0; fs < 2; ++fs)
#pragma unroll
            for (int ft = 0; ft < 2; ++ft) {
                acc[fs][ft] = (f32x4){0.f, 0.f, 0.f, 0.f};
#pragma unroll
                for (int kc = 0; kc < 2; ++kc)
                    acc[fs][ft] = MFMA_BF16(qh[fs][kc], kh[ft][kc], acc[fs][ft]);
            }
        if (s0 + 64 < S_LEN) loadQ(s0 + 64 + ws * 32);   // prefetch next s-tile

#pragma unroll
        for (int fs = 0; fs < 2; ++fs)
#pragma unroll
            for (int ft = 0; ft < 2; ++ft)
#pragma unroll
                for (int i = 0; i < 4; ++i) {
                    float d2 = q2v[fs][i] + k2v[ft] - 2.0f * acc[fs][ft][i];
                    colacc[ft] += compat_fn(d2);
                }
    }
#pragma unroll
    for (int ft = 0; ft < 2; ++ft) {
        colacc[ft] += __shfl_xor(colacc[ft], 16);
        colacc[ft] += __shfl_xor(colacc[ft], 32);
    }
    __shared__ float cs[4][64];
    if (lg == 0) {
        cs[wave][wt * 32 + l15]      = colacc[0];
        cs[wave][wt * 32 + 16 + l15] = colacc[1];
    }
    __syncthreads();
    if (tid < 64) {
        int wtj = tid >> 5;
        float s = cs[wtj][tid] + cs[wtj + 2][tid];
        CV[(size_t)bh * S_LEN + t0 + tid] = 1.0f / __builtin_amdgcn_sqrtf(s);
    }
}

// Pass B: flash-style. QK hi/lo (3-MFMA, d2-sensitive); PV single-bf16.
// K prefetched one iter ahead; V+scalars loaded at iter top; W double-buffered
// in LDS -> ONE barrier per iter; XCD swizzle.
__global__ __launch_bounds__(256, 3) void attn_mfma(
    const u16* __restrict__ Qhi, const u16* __restrict__ Qlo,
    const u16* __restrict__ Khi, const u16* __restrict__ Klo,
    const u16* __restrict__ VThi,
    const float* __restrict__ q2, const float* __restrict__ k2,
    const float* __restrict__ CV,
    u16* __restrict__ ATTNhi, u16* __restrict__ ATTNlo) {
    __shared__ __align__(16) u16 Wb[2][64][72];   // double-buffered [s][t]
    __shared__ float rsum[2][64];
    const int tid  = threadIdx.x;
    const int wave = tid >> 6, lane = tid & 63;
    const int ws = wave >> 1, wt = wave & 1;
    const int l15 = lane & 15, lg = lane >> 4;
    const int flat = blockIdx.y * 32 + blockIdx.x;
    const int swz  = (flat & 7) * 256 + (flat >> 3);
    const int bh = swz >> 5;
    const int s0 = (swz & 31) * 64;
    const int b = bh >> 4, h = bh & 15;
    const size_t base = (size_t)bh * S_LEN * DK;
    const u16* Qh = Qhi + base;
    const u16* Ql = Qlo + base;
    const u16* Kh = Khi + base;
    const u16* Kl = Klo + base;
    const u16* Vh = VThi + base;   // per-bh [64][2048]
    const float* q2b = q2 + (size_t)bh * S_LEN;
    const float* k2b = k2 + (size_t)bh * S_LEN;
    const float* CVb = CV + (size_t)bh * S_LEN;

    s16x8 qh[2][2], qlr[2][2];
#pragma unroll
    for (int fs = 0; fs < 2; ++fs) {
        const int qr = s0 + ws * 32 + fs * 16 + l15;
#pragma unroll
        for (int kc = 0; kc < 2; ++kc) {
            qh[fs][kc]  = *(const s16x8*)(Qh + (size_t)qr * DK + kc * 32 + lg * 8);
            qlr[fs][kc] = *(const s16x8*)(Ql + (size_t)qr * DK + kc * 32 + lg * 8);
        }
    }
    float q2v[2][4];
#pragma unroll
    for (int fs = 0; fs < 2; ++fs)
#pragma unroll
        for (int i = 0; i < 4; ++i)
            q2v[fs][i] = q2b[s0 + ws * 32 + fs * 16 + lg * 4 + i];

    s16x8 kh[2][2], kl[2][2];
    auto loadK = [&](int tc) {
#pragma unroll
        for (int ft = 0; ft < 2; ++ft) {
            const int tr = tc + wt * 32 + ft * 16 + l15;
#pragma unroll
            for (int kc = 0; kc < 2; ++kc) {
                kh[ft][kc] = *(const s16x8*)(Kh + (size_t)tr * DK + kc * 32 + lg * 8);
                kl[ft][kc] = *(const s16x8*)(Kl + (size_t)tr * DK + kc * 32 + lg * 8);
            }
        }
    };
    loadK(0);

    f32x4 o[2][2];
#pragma unroll
    for (int fs = 0; fs < 2; ++fs)
#pragma unroll
        for (int fd = 0; fd < 2; ++fd)
            o[fs][fd] = (f32x4){0.f, 0.f, 0.f, 0.f};
    float rowacc[2][4] = {};

#pragma unroll 1
    for (int t0 = 0; t0 < S_LEN; t0 += 64) {
        const int buf = (t0 >> 6) & 1;
        // V (single-bf16) + scalars for CURRENT iter: consumed after QK/barrier
        s16x8 vv[2][2];
#pragma unroll
        for (int fd = 0; fd < 2; ++fd) {
            const int dr = wt * 32 + fd * 16 + l15;
#pragma unroll
            for (int kc = 0; kc < 2; ++kc)
                vv[fd][kc] = *(const s16x8*)(Vh + (size_t)dr * S_LEN + t0 + kc * 32 + lg * 8);
        }
        float k2v[2], cv2[2];
#pragma unroll
        for (int ft = 0; ft < 2; ++ft) {
            const int tr = t0 + wt * 32 + ft * 16 + l15;
            k2v[ft] = k2b[tr];
            cv2[ft] = CVb[tr];
        }

        // QK^T with K loaded LAST iter (already resident)
        f32x4 acc[2][2];
#pragma unroll
        for (int fs = 0; fs < 2; ++fs)
#pragma unroll
            for (int ft = 0; ft < 2; ++ft) {
                acc[fs][ft] = (f32x4){0.f, 0.f, 0.f, 0.f};
#pragma unroll
                for (int kc = 0; kc < 2; ++kc) {
                    acc[fs][ft] = MFMA_BF16(qh[fs][kc],  kh[ft][kc], acc[fs][ft]);
                    acc[fs][ft] = MFMA_BF16(qh[fs][kc],  kl[ft][kc], acc[fs][ft]);
                    acc[fs][ft] = MFMA_BF16(qlr[fs][kc], kh[ft][kc], acc[fs][ft]);
                }
            }
        // prefetch NEXT K tile (lands during compat+barrier+PV)
        if (t0 + 64 < S_LEN) loadK(t0 + 64);

        // compat -> w -> LDS (single bf16)
#pragma unroll
        for (int fs = 0; fs < 2; ++fs)
#pragma unroll
            for (int ft = 0; ft < 2; ++ft)
#pragma unroll
                for (int i = 0; i < 4; ++i) {
                    float d2 = q2v[fs][i] + k2v[ft] - 2.0f * acc[fs][ft][i];
                    float w  = compat_fn(d2) * cv2[ft];
                    rowacc[fs][i] += w;
                    Wb[buf][ws * 32 + fs * 16 + lg * 4 + i][wt * 32 + ft * 16 + l15] = f2bf(w);
                }
        __syncthreads();   // W[buf] complete (prev-iter reads were from buf^1)

        // PV: read W fragments, single-bf16 MFMA with V
        s16x8 wh[2][2];
#pragma unroll
        for (int fs = 0; fs < 2; ++fs) {
            const int sl = ws * 32 + fs * 16 + l15;
#pragma unroll
            for (int kc = 0; kc < 2; ++kc)
                wh[fs][kc] = *(const s16x8*)&Wb[buf][sl][kc * 32 + lg * 8];
        }
#pragma unroll
        for (int fs = 0; fs < 2; ++fs)
#pragma unroll
            for (int fd = 0; fd < 2; ++fd)
#pragma unroll
                for (int kc = 0; kc < 2; ++kc)
                    o[fs][fd] = MFMA_BF16(wh[fs][kc], vv[fd][kc], o[fs][fd]);
    }

    // row sums: reduce 16 column-lanes, then the two wt waves
#pragma unroll
    for (int fs = 0; fs < 2; ++fs)
#pragma unroll
        for (int i = 0; i < 4; ++i) {
            float r = rowacc[fs][i];
            r += __shfl_xor(r, 1);
            r += __shfl_xor(r, 2);
            r += __shfl_xor(r, 4);
            r += __shfl_xor(r, 8);
            rowacc[fs][i] = r;
        }
    if (l15 == 0) {
#pragma unroll
        for (int fs = 0; fs < 2; ++fs)
#pragma unroll
            for (int i = 0; i < 4; ++i)
                rsum[wt][ws * 32 + fs * 16 + lg * 4 + i] = rowacc[fs][i];
    }
    __syncthreads();

#pragma unroll
    for (int fs = 0; fs < 2; ++fs)
#pragma unroll
        for (int i = 0; i < 4; ++i) {
            const int sl   = ws * 32 + fs * 16 + lg * 4 + i;
            const float inv = 1.0f / (rsum[0][sl] + rsum[1][sl]);
            const int srow = s0 + sl;
#pragma unroll
            for (int fd = 0; fd < 2; ++fd) {
                const int d = wt * 32 + fd * 16 + l15;
                float v = o[fs][fd][i] * inv;
                u16 hb = f2bf(v);
                u16 lb = f2bf(v - bf2f(hb));
                size_t idx = ((size_t)(b * S_LEN + srow)) * D_MODEL + h * DK + d;
                ATTNhi[idx] = hb;
                ATTNlo[idx] = lb;
            }
        }
}

extern "C" void kernel_launch(void* const* d_in, const int* in_sizes, int n_in,
                              void* d_out, int out_size, void* d_ws, size_t ws_size,
                              hipStream_t stream) {
    const float* queries = (const float*)d_in[0];
    const float* keys    = (const float*)d_in[1];
    const float* values  = (const float*)d_in[2];
    const float* Wq      = (const float*)d_in[3];
    const float* Wk      = (const float*)d_in[4];
    const float* Wv      = (const float*)d_in[5];
    const float* Wo      = (const float*)d_in[6];
    const float* bo      = (const float*)d_in[7];
    float* out = (float*)d_out;

    const size_t NW = (size_t)D_MODEL * D_MODEL;     // 1,048,576
    const size_t NX = (size_t)M_ROWS * D_MODEL;      // 8,388,608
    u16* base = (u16*)d_ws;
    size_t off = 0;
    auto take = [&](size_t n) { u16* r = base + off; off += n; return r; };
    u16 *Wqh = take(NW), *Wql = take(NW), *Wkh = take(NW), *Wkl = take(NW);
    u16 *Wvh = take(NW), *Wvl = take(NW), *Woh = take(NW), *Wol = take(NW);
    u16 *Xqh = take(NX), *Xql = take(NX);
    u16 *Xkh = take(NX), *Xkl = take(NX);
    u16 *Xvh = take(NX), *Xvl = take(NX);
    u16 *Qhi = take(NX), *Qlo = take(NX), *Khi = take(NX), *Klo = take(NX);
    u16 *VThi = take(NX);
    // reuse regions dead by the time these are written:
    u16* ATTNhi = Xqh;                 // dead after Q projection
    u16* ATTNlo = Xql;
    float* q2  = (float*)Xkh;          // dead after K projection
    float* k2  = q2 + (size_t)BH * S_LEN;
    float* CVa = k2 + (size_t)BH * S_LEN;

    // 1) split inputs/weights into hi/lo bf16
    split_bf16<<<(int)(NX / 8 / 256), 256, 0, stream>>>(queries, Xqh, Xql, (int)(NX / 8));
    split_bf16<<<(int)(NX / 8 / 256), 256, 0, stream>>>(keys,    Xkh, Xkl, (int)(NX / 8));
    split_bf16<<<(int)(NX / 8 / 256), 256, 0, stream>>>(values,  Xvh, Xvl, (int)(NX / 8));
    split_bf16<<<(int)(NW / 8 / 256), 256, 0, stream>>>(Wq, Wqh, Wql, (int)(NW / 8));
    split_bf16<<<(int)(NW / 8 / 256), 256, 0, stream>>>(Wk, Wkh, Wkl, (int)(NW / 8));
    split_bf16<<<(int)(NW / 8 / 256), 256, 0, stream>>>(Wv, Wvh, Wvl, (int)(NW / 8));
    split_bf16<<<(int)(NW / 8 / 256), 256, 0, stream>>>(Wo, Woh, Wol, (int)(NW / 8));

    // 2) projections (MFMA split-bf16)
    dim3 gproj(D_MODEL / 128, M_ROWS / 128);   // (8, 64)
    proj_mfma<0><<<gproj, 256, 0, stream>>>(Xqh, Xql, Wqh, Wql, nullptr, nullptr, Qhi, Qlo);
    proj_mfma<0><<<gproj, 256, 0, stream>>>(Xkh, Xkl, Wkh, Wkl, nullptr, nullptr, Khi, Klo);
    proj_mfma<2><<<gproj, 256, 0, stream>>>(Xvh, Xvl, Wvh, Wvl, nullptr, nullptr, VThi, nullptr);

    // 3) row norms
    row_norms<<<(2 * BH * S_LEN) / 4, 256, 0, stream>>>(Qhi, Qlo, Khi, Klo, q2, k2);

    // 4) column sums -> CV, then flash-style attention
    dim3 gpass(S_LEN / 64, BH);                // (32, 64)
    colsum_mfma<<<gpass, 256, 0, stream>>>(Qhi, Khi, q2, k2, CVa);
    attn_mfma<<<gpass, 256, 0, stream>>>(Qhi, Qlo, Khi, Klo, VThi, q2, k2, CVa, ATTNhi, ATTNlo);

    // 5) output projection + bias
    proj_mfma<1><<<gproj, 256, 0, stream>>>(ATTNhi, ATTNlo, Woh, Wol, bo, out, nullptr, nullptr);
}